// Round 13
// baseline (406.035 us; speedup 1.0000x reference)
//
#include <hip/hip_runtime.h>

#define NNODES 50000
#define HEADS 3
#define NBUCK 196          // ceil(50000/256)
#define BCAP  16320        // per-bucket edge capacity (avg 8163)

typedef __attribute__((ext_vector_type(8))) short bf16x8;
typedef __attribute__((ext_vector_type(4))) float f32x4;

__device__ __forceinline__ float wred_sum(float v){
  #pragma unroll
  for (int s = 32; s > 0; s >>= 1) v += __shfl_xor(v, s, 64);
  return v;
}
__device__ __forceinline__ unsigned short f2bf(float x){
  unsigned int u = __float_as_uint(x);
  unsigned int r = (u + 0x7FFFu + ((u >> 16) & 1u)) >> 16;
  return (unsigned short)r;
}

// ---------------- W -> MFMA-fragment bf16 (+folded el/er); layer 3 = zero bcur
__global__ __launch_bounds__(256) void prep_b_all_kernel(
    const float* __restrict__ W0, const float* __restrict__ al0, const float* __restrict__ ar0,
    const float* __restrict__ W1, const float* __restrict__ al1, const float* __restrict__ ar1,
    const float* __restrict__ W2, const float* __restrict__ al2, const float* __restrict__ ar2,
    unsigned short* __restrict__ BfAll, int* __restrict__ bcur)
{
  const int layer = blockIdx.y;
  if (layer == 3) {
    if (blockIdx.x == 0) {
      int i = threadIdx.x;
      if (i < NBUCK) bcur[i] = 0;
    }
    return;
  }
  const float *W, *al, *ar;
  int K, NT, NCf, F; unsigned short* Bf;
  if (layer == 0) { W=W0; al=al0; ar=ar0; K=256; NT=13; NCf=192; F=64; Bf=BfAll; }
  else if (layer == 1) { W=W1; al=al1; ar=ar1; K=192; NT=13; NCf=192; F=64; Bf=BfAll+53248; }
  else { W=W2; al=al2; ar=ar2; K=192; NT=8; NCf=120; F=40; Bf=BfAll+93184; }

  int tid = blockIdx.x * 256 + threadIdx.x;
  int total = (K >> 5) * NT * 64;
  if (tid >= total) return;
  int l  = tid & 63;
  int t  = (tid >> 6) % NT;
  int kc = tid / (NT * 64);
  int k0  = kc * 32 + (l >> 4) * 8;
  int col = t * 16 + (l & 15);
  unsigned short o[8];
  #pragma unroll
  for (int j = 0; j < 8; ++j) {
    int k = k0 + j;
    float v = 0.f;
    if (col < NCf) {
      v = W[(size_t)k * NCf + col];
    } else if (col < NCf + 6) {
      int c = col - NCf;
      int h = (c < 3) ? c : c - 3;
      const float* av = ((c < 3) ? al : ar) + h * F;
      const float* wp = W + (size_t)k * NCf + h * F;
      float a = 0.f;
      for (int f = 0; f < F; ++f) a += wp[f] * av[f];
      v = a;
    }
    o[j] = f2bf(v);
  }
  ushort4* dst = (ushort4*)&Bf[(size_t)tid * 8];
  dst[0] = make_ushort4(o[0], o[1], o[2], o[3]);
  dst[1] = make_ushort4(o[4], o[5], o[6], o[7]);
}

// ---------------- MFMA GEMM: 32-row tiles, LDS-staged A (swizzled) --------
// AF32=1: A fp32 (cvt fused in stage, OOB rows zeroed). AF32=0: A bf16 (ws,
// padded; stage loads unguarded, stores guarded). B loads inline (compiler
// schedules; explicit dbuf costs 64 VGPR and occupancy).
template<int KK, int AF32>
__global__ __launch_bounds__(256) void gemm_mfma_kernel(
    const void* __restrict__ Ap, const unsigned short* __restrict__ Bf,
    unsigned short* __restrict__ Cb, float* __restrict__ elp, float* __restrict__ erp,
    int M, int NT, int NCf)
{
  constexpr int ROWB = KK * 2;             // bf16 bytes per row
  __shared__ unsigned short atile[32 * KK];
  const int t = threadIdx.x;
  const int w = t >> 6, l = t & 63;
  const int lrow = l & 15, kg = l >> 4;
  const int r0 = blockIdx.x * 32;
  const bf16x8* Bfv = (const bf16x8*)Bf;

  // stage 32-row A-tile into LDS with XOR swizzle (colb ^ ((row&7)<<4))
  {
    char* lbase = (char*)atile;
    #pragma unroll
    for (int i = 0; i < (32 * ROWB) / 4096; ++i) {
      int o = i * 4096 + t * 16;     // bf16-byte offset within tile
      int row = o / ROWB;
      int colb = o - row * ROWB;
      uint4 v = {0u, 0u, 0u, 0u};
      if (AF32) {
        int grow = r0 + row;
        if (grow < M) {
          const char* gsrc = (const char*)Ap + (size_t)grow * (KK * 4) + (size_t)colb * 2;
          const float4 f0 = *(const float4*)gsrc;
          const float4 f1 = *(const float4*)(gsrc + 16);
          v.x = (unsigned)f2bf(f0.x) | ((unsigned)f2bf(f0.y) << 16);
          v.y = (unsigned)f2bf(f0.z) | ((unsigned)f2bf(f0.w) << 16);
          v.z = (unsigned)f2bf(f1.x) | ((unsigned)f2bf(f1.y) << 16);
          v.w = (unsigned)f2bf(f1.z) | ((unsigned)f2bf(f1.w) << 16);
        }
      } else {
        const char* gsrc = (const char*)Ap + (size_t)r0 * ROWB;
        v = *(const uint4*)(gsrc + o);
      }
      *(uint4*)(lbase + row * ROWB + (colb ^ ((row & 7) << 4))) = v;
    }
  }

  f32x4 acc[2][4];
  #pragma unroll
  for (int mt = 0; mt < 2; ++mt)
    #pragma unroll
    for (int j = 0; j < 4; ++j)
      acc[mt][j] = (f32x4){0.f, 0.f, 0.f, 0.f};

  constexpr int nkc = KK / 32;

  __syncthreads();

  for (int kc = 0; kc < nkc; ++kc) {
    bf16x8 af[2];
    #pragma unroll
    for (int mt = 0; mt < 2; ++mt) {
      int row_l = mt * 16 + lrow;
      int colb  = kc * 64 + kg * 16;
      af[mt] = *(const bf16x8*)((const char*)atile + row_l * ROWB + (colb ^ ((row_l & 7) << 4)));
    }
    #pragma unroll
    for (int j = 0; j < 4; ++j) {
      int tile = w + 4 * j;
      if (tile < NT) {
        bf16x8 bfr = Bfv[((size_t)kc * NT + tile) * 64 + l];
        #pragma unroll
        for (int mt = 0; mt < 2; ++mt)
          acc[mt][j] = __builtin_amdgcn_mfma_f32_16x16x32_bf16(af[mt], bfr, acc[mt][j], 0, 0, 0);
      }
    }
  }

  // epilogue: pack 4 cols/lane-quad -> uint2 stores; el/er scalar
  #pragma unroll
  for (int j = 0; j < 4; ++j) {
    int tile = w + 4 * j;
    if (tile >= NT) continue;
    int c = tile * 16 + lrow;
    #pragma unroll
    for (int mt = 0; mt < 2; ++mt) {
      #pragma unroll
      for (int rr = 0; rr < 4; ++rr) {
        int row = r0 + mt * 16 + kg * 4 + rr;
        float v = acc[mt][j][rr];
        float v1 = __shfl_xor(v, 1, 64);
        unsigned p01 = (unsigned)f2bf(v) | ((unsigned)f2bf(v1) << 16);
        unsigned p23 = __shfl_xor(p01, 2, 64);
        if (row < M) {
          if ((lrow & 3) == 0 && c + 3 < NCf)
            *(uint2*)&Cb[(size_t)row * NCf + c] = make_uint2(p01, p23);
          else if (c >= NCf && c < NCf + 3)       elp[row * 4 + (c - NCf)] = v;
          else if (c >= NCf + 3 && c < NCf + 6)   erp[row * 4 + (c - NCf - 3)] = v;
        }
      }
    }
  }
}

// ---------------- CSR build: bucket partition (packed uint payload) -------
// payload: bits [15:0] = src (N < 65536), bits [23:16] = dst & 255.
__global__ __launch_bounds__(256) void partition_kernel(
    const int* __restrict__ src, const int* __restrict__ dst,
    int* __restrict__ bcur, unsigned* __restrict__ ebuf, int E)
{
  __shared__ int hist[NBUCK];
  __shared__ int gbase[NBUCK];
  const int t = threadIdx.x;
  const int e0 = blockIdx.x * 2048;
  for (int i = t; i < NBUCK; i += 256) hist[i] = 0;
  __syncthreads();
  int  b_[8], r_[8];
  unsigned p_[8];
  #pragma unroll
  for (int v = 0; v < 8; ++v) {
    int e = e0 + v * 256 + t;
    b_[v] = -1;
    if (e < E) {
      int s = src[e], d = dst[e];
      p_[v] = (unsigned)s | ((unsigned)(d & 255) << 16);
      b_[v] = d >> 8;
      r_[v] = atomicAdd(&hist[b_[v]], 1);
    }
  }
  __syncthreads();
  for (int i = t; i < NBUCK; i += 256) {
    int h = hist[i];
    gbase[i] = h ? atomicAdd(&bcur[i], h) : 0;
  }
  __syncthreads();
  #pragma unroll
  for (int v = 0; v < 8; ++v)
    if (b_[v] >= 0)
      ebuf[(size_t)b_[v] * BCAP + gbase[b_[v]] + r_[v]] = p_[v];
}

// One WG per bucket; computes its own base via local prefix over bcur,
// builds off[] via LDS histogram+scan, then L2-local scatter into adj.
__global__ __launch_bounds__(256) void fill_local_kernel(
    const unsigned* __restrict__ ebuf, const int* __restrict__ bcur,
    int* __restrict__ off, int* __restrict__ adj, int N)
{
  __shared__ int lhist[256], loff[256], lcur[256];
  __shared__ int wsum[4];
  __shared__ int sbase;
  const int b = blockIdx.x;
  const int t = threadIdx.x;
  const int wv = t >> 6, l = t & 63;
  const int cnt = bcur[b];
  const unsigned* seg = ebuf + (size_t)b * BCAP;

  {
    int v = (t < NBUCK) ? bcur[t] : 0;
    int x = v;
    #pragma unroll
    for (int s = 1; s < 64; s <<= 1) {
      int y = __shfl_up(x, s, 64);
      if (l >= s) x += y;
    }
    if (l == 63) wsum[wv] = x;
    lhist[t] = 0; lcur[t] = 0;
    __syncthreads();
    int woff = 0;
    #pragma unroll
    for (int k = 0; k < 4; ++k) woff += (k < wv) ? wsum[k] : 0;
    if (t == b) sbase = woff + x - v;
  }
  __syncthreads();

  for (int i = t; i < cnt; i += 256)
    atomicAdd(&lhist[(seg[i] >> 16) & 255], 1);
  __syncthreads();

  int v = lhist[t];
  int x = v;
  #pragma unroll
  for (int s = 1; s < 64; s <<= 1) {
    int y = __shfl_up(x, s, 64);
    if (l >= s) x += y;
  }
  if (l == 63) wsum[wv] = x;
  __syncthreads();
  int woff = 0;
  #pragma unroll
  for (int k = 0; k < 4; ++k) woff += (k < wv) ? wsum[k] : 0;
  loff[t] = woff + x - v;
  int gd = (b << 8) + t;
  if (gd <= N) off[gd] = sbase + loff[t];
  __syncthreads();
  const int base = sbase;
  for (int i = t; i < cnt; i += 256) {
    unsigned p = seg[i];
    int d = (p >> 16) & 255;
    int r = atomicAdd(&lcur[d], 1);
    adj[base + loff[d] + r] = (int)(p & 0xFFFFu);
  }
}

// ---------------- aggregation: one wave per dst node (fabric-floor-bound) --
__global__ __launch_bounds__(256) void aggregate_kernel(
    const unsigned short* __restrict__ featb, const int* __restrict__ adj,
    const int* __restrict__ off, const float* __restrict__ elp,
    const float* __restrict__ erp, void* __restrict__ outp,
    int N, int F, int mode)
{
  __shared__ float4 pl[4][64];
  int wv = threadIdx.x >> 6, l = threadIdx.x & 63;
  int n  = blockIdx.x * 4 + wv;
  if (n >= N) return;
  const int NC = HEADS * F;
  const unsigned rowbytes = NC * 2;
  int o0 = off[n], d = off[n + 1] - o0;
  float er0 = erp[n * 4 + 0], er1 = erp[n * 4 + 1], er2 = erp[n * 4 + 2];
  const float4* elv = (const float4*)elp;
  const char* fbase = (const char*)featb;
  const int gl = (F == 64) ? 48 : 30;
  const int h  = (F == 64) ? (l >> 4) : (l / 10);
  const unsigned loff2 = (unsigned)l * 8u;
  const float4* plw = pl[wv];

  float s0 = 0.f, s1 = 0.f, s2 = 0.f;
  float4 acc = {0.f, 0.f, 0.f, 0.f};

#define LDU(AA) (*(const uint2*)(fbase + (__float_as_uint((AA).x) + loff2)))
#define FMA4(AA, UU) { \
    float ww = (h == 0) ? (AA).y : (h == 1) ? (AA).z : (AA).w; \
    acc.x += ww * __uint_as_float((UU).x << 16); \
    acc.y += ww * __uint_as_float((UU).x & 0xffff0000u); \
    acc.z += ww * __uint_as_float((UU).y << 16); \
    acc.w += ww * __uint_as_float((UU).y & 0xffff0000u); }

  for (int base = 0; base < d; base += 64) {
    int i = base + l;
    float p0 = 0.f, p1 = 0.f, p2 = 0.f;
    unsigned boff = 0;
    if (i < d) {
      int ssrc = adj[o0 + i];
      boff = (unsigned)ssrc * rowbytes;
      float4 ev = elv[ssrc];
      float x0 = ev.x + er0; x0 = fmaxf(x0, 0.2f * x0);
      float x1 = ev.y + er1; x1 = fmaxf(x1, 0.2f * x1);
      float x2 = ev.z + er2; x2 = fmaxf(x2, 0.2f * x2);
      p0 = __expf(x0); p1 = __expf(x1); p2 = __expf(x2);
    }
    s0 += p0; s1 += p1; s2 += p2;
    pl[wv][l] = make_float4(__uint_as_float(boff), p0, p1, p2);

    int cnt = min(64, d - base);
    if (l < gl) {
      int e = 0;
      if (cnt >= 8) {
        float4 a0 = plw[0], a1 = plw[1], a2 = plw[2], a3 = plw[3];
        uint2 u0 = LDU(a0), u1 = LDU(a1), u2 = LDU(a2), u3 = LDU(a3);
        for (e = 4; e + 4 <= cnt; e += 4) {
          float4 b0 = plw[e], b1 = plw[e + 1], b2 = plw[e + 2], b3 = plw[e + 3];
          uint2 n0 = LDU(b0), n1 = LDU(b1), n2 = LDU(b2), n3 = LDU(b3);
          FMA4(a0, u0) FMA4(a1, u1) FMA4(a2, u2) FMA4(a3, u3)
          a0 = b0; a1 = b1; a2 = b2; a3 = b3;
          u0 = n0; u1 = n1; u2 = n2; u3 = n3;
        }
        FMA4(a0, u0) FMA4(a1, u1) FMA4(a2, u2) FMA4(a3, u3)
      }
      for (; e < cnt; ++e) {
        float4 a0 = plw[e];
        uint2 u0 = LDU(a0);
        FMA4(a0, u0)
      }
    }
  }
#undef LDU
#undef FMA4

  s0 = wred_sum(s0); s1 = wred_sum(s1); s2 = wred_sum(s2);
  float i0 = s0 > 0.f ? 1.f / s0 : 0.f;
  float i1 = s1 > 0.f ? 1.f / s1 : 0.f;
  float i2 = s2 > 0.f ? 1.f / s2 : 0.f;
  float ih = (h == 0) ? i0 : (h == 1) ? i1 : i2;
  acc.x *= ih; acc.y *= ih; acc.z *= ih; acc.w *= ih;

  if (mode == 0) {
    if (l < 48) {
      ushort4 o;
      o.x = f2bf(fmaxf(acc.x, 0.f)); o.y = f2bf(fmaxf(acc.y, 0.f));
      o.z = f2bf(fmaxf(acc.z, 0.f)); o.w = f2bf(fmaxf(acc.w, 0.f));
      *(ushort4*)((unsigned short*)outp + (size_t)n * 192 + l * 4) = o;
    }
  } else {
    float bx = __shfl(acc.x, l + 10, 64), cx = __shfl(acc.x, l + 20, 64);
    float by = __shfl(acc.y, l + 10, 64), cy = __shfl(acc.y, l + 20, 64);
    float bz = __shfl(acc.z, l + 10, 64), cz = __shfl(acc.z, l + 20, 64);
    float bw = __shfl(acc.w, l + 10, 64), cw = __shfl(acc.w, l + 20, 64);
    if (l < 10) {
      float4 o;
      o.x = (acc.x + bx + cx) * (1.f / 3.f);
      o.y = (acc.y + by + cy) * (1.f / 3.f);
      o.z = (acc.z + bz + cz) * (1.f / 3.f);
      o.w = (acc.w + bw + cw) * (1.f / 3.f);
      *(float4*)((float*)outp + (size_t)n * 40 + l * 4) = o;
    }
  }
}

extern "C" void kernel_launch(void* const* d_in, const int* in_sizes, int n_in,
                              void* d_out, int out_size, void* d_ws, size_t ws_size,
                              hipStream_t stream) {
  const float* x   = (const float*)d_in[0];
  const int*   src = (const int*)d_in[1];
  const int*   dst = (const int*)d_in[2];
  const float* W0  = (const float*)d_in[3];
  const float* al0 = (const float*)d_in[4];
  const float* ar0 = (const float*)d_in[5];
  const float* W1  = (const float*)d_in[6];
  const float* al1 = (const float*)d_in[7];
  const float* ar1 = (const float*)d_in[8];
  const float* W2  = (const float*)d_in[9];
  const float* al2 = (const float*)d_in[10];
  const float* ar2 = (const float*)d_in[11];
  const int N = NNODES;
  const int E = in_sizes[1];
  float* out = (float*)d_out;

  char* w = (char*)d_ws;
  unsigned*       ebuf  = (unsigned*)w;       w += (size_t)NBUCK * BCAP * 4;    // 12.8MB
  unsigned short* featb = (unsigned short*)w; w += (size_t)N * 192 * 2;         // 19.2MB
  unsigned short* aggb  = (unsigned short*)w; w += (size_t)N * 192 * 2 + 65536; // 19.2MB+pad (OOB stage reads)
  unsigned short* Bf    = (unsigned short*)w; w += (size_t)256 * 1024;          // 256KB
  float* elp = (float*)w; w += (size_t)N * 4 * 4;
  float* erp = (float*)w; w += (size_t)N * 4 * 4;
  int* off   = (int*)w;  w += (size_t)(N + 1) * 4;
  int* adj   = (int*)w;  w += (size_t)E * 4;
  int* bcur  = (int*)w;  w += (size_t)NBUCK * 4;

  // weight prep (layers 0-2) + bcur zeroing (layer 3) in one launch
  prep_b_all_kernel<<<dim3(26, 4), 256, 0, stream>>>(W0, al0, ar0, W1, al1, ar1,
                                                     W2, al2, ar2, Bf, bcur);

  // CSR build via bucket partition (all scatters L2-local)
  partition_kernel<<<(E + 2047) / 2048, 256, 0, stream>>>(src, dst, bcur, ebuf, E);
  fill_local_kernel<<<NBUCK, 256, 0, stream>>>(ebuf, bcur, off, adj, N);

  int gblk = (N + 31) / 32;
  int ablk = (N + 3) / 4;

  // layer 0: fp32 A, cvt fused into LDS stage; K=256, NT=13 (192 feat + el/er)
  gemm_mfma_kernel<256, 1><<<gblk, 256, 0, stream>>>(x, Bf, featb, elp, erp, N, 13, 192);
  aggregate_kernel<<<ablk, 256, 0, stream>>>(featb, adj, off, elp, erp, aggb, N, 64, 0);
  // layer 1: K=192, NT=13
  gemm_mfma_kernel<192, 0><<<gblk, 256, 0, stream>>>(aggb, Bf + 53248, featb, elp, erp, N, 13, 192);
  aggregate_kernel<<<ablk, 256, 0, stream>>>(featb, adj, off, elp, erp, aggb, N, 64, 0);
  // layer 2: K=192, NT=8 (120 feat cols + el/er in tile 7)
  gemm_mfma_kernel<192, 0><<<gblk, 256, 0, stream>>>(aggb, Bf + 93184, featb, elp, erp, N, 8, 120);
  aggregate_kernel<<<ablk, 256, 0, stream>>>(featb, adj, off, elp, erp, out, N, 40, 1);
}

// Round 14
// 395.604 us; speedup vs baseline: 1.0264x; 1.0264x over previous
//
#include <hip/hip_runtime.h>

#define NNODES 50000
#define HEADS 3
#define NBUCK 196          // ceil(50000/256)
#define BCAP  16320        // per-bucket edge capacity (avg 8163)

typedef __attribute__((ext_vector_type(8))) short bf16x8;
typedef __attribute__((ext_vector_type(4))) float f32x4;

__device__ __forceinline__ float wred_sum(float v){
  #pragma unroll
  for (int s = 32; s > 0; s >>= 1) v += __shfl_xor(v, s, 64);
  return v;
}
__device__ __forceinline__ unsigned short f2bf(float x){
  unsigned int u = __float_as_uint(x);
  unsigned int r = (u + 0x7FFFu + ((u >> 16) & 1u)) >> 16;
  return (unsigned short)r;
}

// ---------------- W -> MFMA-fragment bf16 (+folded el/er); layer 3 = zero bcur
__global__ __launch_bounds__(256) void prep_b_all_kernel(
    const float* __restrict__ W0, const float* __restrict__ al0, const float* __restrict__ ar0,
    const float* __restrict__ W1, const float* __restrict__ al1, const float* __restrict__ ar1,
    const float* __restrict__ W2, const float* __restrict__ al2, const float* __restrict__ ar2,
    unsigned short* __restrict__ BfAll, int* __restrict__ bcur)
{
  const int layer = blockIdx.y;
  if (layer == 3) {
    if (blockIdx.x == 0) {
      int i = threadIdx.x;
      if (i < NBUCK) bcur[i] = 0;
    }
    return;
  }
  const float *W, *al, *ar;
  int K, NT, NCf, F; unsigned short* Bf;
  if (layer == 0) { W=W0; al=al0; ar=ar0; K=256; NT=13; NCf=192; F=64; Bf=BfAll; }
  else if (layer == 1) { W=W1; al=al1; ar=ar1; K=192; NT=13; NCf=192; F=64; Bf=BfAll+53248; }
  else { W=W2; al=al2; ar=ar2; K=192; NT=8; NCf=120; F=40; Bf=BfAll+93184; }

  int tid = blockIdx.x * 256 + threadIdx.x;
  int total = (K >> 5) * NT * 64;
  if (tid >= total) return;
  int l  = tid & 63;
  int t  = (tid >> 6) % NT;
  int kc = tid / (NT * 64);
  int k0  = kc * 32 + (l >> 4) * 8;
  int col = t * 16 + (l & 15);
  unsigned short o[8];
  #pragma unroll
  for (int j = 0; j < 8; ++j) {
    int k = k0 + j;
    float v = 0.f;
    if (col < NCf) {
      v = W[(size_t)k * NCf + col];
    } else if (col < NCf + 6) {
      int c = col - NCf;
      int h = (c < 3) ? c : c - 3;
      const float* av = ((c < 3) ? al : ar) + h * F;
      const float* wp = W + (size_t)k * NCf + h * F;
      float a = 0.f;
      for (int f = 0; f < F; ++f) a += wp[f] * av[f];
      v = a;
    }
    o[j] = f2bf(v);
  }
  ushort4* dst = (ushort4*)&Bf[(size_t)tid * 8];
  dst[0] = make_ushort4(o[0], o[1], o[2], o[3]);
  dst[1] = make_ushort4(o[4], o[5], o[6], o[7]);
}

// ---------------- MFMA GEMM: 32-row tiles, LDS-staged A (swizzled) --------
// AF32=1: A fp32 (cvt fused in stage, OOB rows zeroed). AF32=0: A bf16 (ws,
// padded; stage loads unguarded, stores guarded). B explicitly double-buffered
// in registers (R13 showed compiler does NOT hoist branch-guarded B loads).
template<int KK, int AF32>
__global__ __launch_bounds__(256) void gemm_mfma_kernel(
    const void* __restrict__ Ap, const unsigned short* __restrict__ Bf,
    unsigned short* __restrict__ Cb, float* __restrict__ elp, float* __restrict__ erp,
    int M, int NT, int NCf)
{
  constexpr int ROWB = KK * 2;             // bf16 bytes per row
  __shared__ unsigned short atile[32 * KK];
  const int t = threadIdx.x;
  const int w = t >> 6, l = t & 63;
  const int lrow = l & 15, kg = l >> 4;
  const int r0 = blockIdx.x * 32;
  const bf16x8* Bfv = (const bf16x8*)Bf;

  // stage 32-row A-tile into LDS with XOR swizzle (colb ^ ((row&7)<<4))
  {
    char* lbase = (char*)atile;
    #pragma unroll
    for (int i = 0; i < (32 * ROWB) / 4096; ++i) {
      int o = i * 4096 + t * 16;     // bf16-byte offset within tile
      int row = o / ROWB;
      int colb = o - row * ROWB;
      uint4 v = {0u, 0u, 0u, 0u};
      if (AF32) {
        int grow = r0 + row;
        if (grow < M) {
          const char* gsrc = (const char*)Ap + (size_t)grow * (KK * 4) + (size_t)colb * 2;
          const float4 f0 = *(const float4*)gsrc;
          const float4 f1 = *(const float4*)(gsrc + 16);
          v.x = (unsigned)f2bf(f0.x) | ((unsigned)f2bf(f0.y) << 16);
          v.y = (unsigned)f2bf(f0.z) | ((unsigned)f2bf(f0.w) << 16);
          v.z = (unsigned)f2bf(f1.x) | ((unsigned)f2bf(f1.y) << 16);
          v.w = (unsigned)f2bf(f1.z) | ((unsigned)f2bf(f1.w) << 16);
        }
      } else {
        const char* gsrc = (const char*)Ap + (size_t)r0 * ROWB;
        v = *(const uint4*)(gsrc + o);
      }
      *(uint4*)(lbase + row * ROWB + (colb ^ ((row & 7) << 4))) = v;
    }
  }

  f32x4 acc[2][4];
  #pragma unroll
  for (int mt = 0; mt < 2; ++mt)
    #pragma unroll
    for (int j = 0; j < 4; ++j)
      acc[mt][j] = (f32x4){0.f, 0.f, 0.f, 0.f};

  constexpr int nkc = KK / 32;
  const bf16x8 bz = {0,0,0,0,0,0,0,0};

  __syncthreads();

  bf16x8 bcur_[4], bnext[4];
  #pragma unroll
  for (int j = 0; j < 4; ++j) {
    int tile = w + 4 * j;
    bcur_[j] = (tile < NT) ? Bfv[(size_t)tile * 64 + l] : bz;
  }

  for (int kc = 0; kc < nkc; ++kc) {
    if (kc + 1 < nkc) {
      #pragma unroll
      for (int j = 0; j < 4; ++j) {
        int tile = w + 4 * j;
        bnext[j] = (tile < NT) ? Bfv[((size_t)(kc + 1) * NT + tile) * 64 + l] : bz;
      }
    }
    bf16x8 af[2];
    #pragma unroll
    for (int mt = 0; mt < 2; ++mt) {
      int row_l = mt * 16 + lrow;
      int colb  = kc * 64 + kg * 16;
      af[mt] = *(const bf16x8*)((const char*)atile + row_l * ROWB + (colb ^ ((row_l & 7) << 4)));
    }
    #pragma unroll
    for (int j = 0; j < 4; ++j) {
      int tile = w + 4 * j;
      if (tile < NT) {
        #pragma unroll
        for (int mt = 0; mt < 2; ++mt)
          acc[mt][j] = __builtin_amdgcn_mfma_f32_16x16x32_bf16(af[mt], bcur_[j], acc[mt][j], 0, 0, 0);
      }
    }
    #pragma unroll
    for (int j = 0; j < 4; ++j) bcur_[j] = bnext[j];
  }

  // epilogue: pack 4 cols/lane-quad -> uint2 stores; el/er scalar
  #pragma unroll
  for (int j = 0; j < 4; ++j) {
    int tile = w + 4 * j;
    if (tile >= NT) continue;
    int c = tile * 16 + lrow;
    #pragma unroll
    for (int mt = 0; mt < 2; ++mt) {
      #pragma unroll
      for (int rr = 0; rr < 4; ++rr) {
        int row = r0 + mt * 16 + kg * 4 + rr;
        float v = acc[mt][j][rr];
        float v1 = __shfl_xor(v, 1, 64);
        unsigned p01 = (unsigned)f2bf(v) | ((unsigned)f2bf(v1) << 16);
        unsigned p23 = __shfl_xor(p01, 2, 64);
        if (row < M) {
          if ((lrow & 3) == 0 && c + 3 < NCf)
            *(uint2*)&Cb[(size_t)row * NCf + c] = make_uint2(p01, p23);
          else if (c >= NCf && c < NCf + 3)       elp[row * 4 + (c - NCf)] = v;
          else if (c >= NCf + 3 && c < NCf + 6)   erp[row * 4 + (c - NCf - 3)] = v;
        }
      }
    }
  }
}

// ---------------- CSR build: bucket partition ----------------
__global__ __launch_bounds__(256) void partition_kernel(
    const int* __restrict__ src, const int* __restrict__ dst,
    int* __restrict__ bcur, uint2* __restrict__ ebuf, int E)
{
  __shared__ int hist[NBUCK];
  __shared__ int gbase[NBUCK];
  const int t = threadIdx.x;
  const int e0 = blockIdx.x * 2048;
  for (int i = t; i < NBUCK; i += 256) hist[i] = 0;
  __syncthreads();
  int  b_[8], r_[8];
  uint2 p_[8];
  #pragma unroll
  for (int v = 0; v < 8; ++v) {
    int e = e0 + v * 256 + t;
    b_[v] = -1;
    if (e < E) {
      int s = src[e], d = dst[e];
      p_[v] = make_uint2((unsigned)s, (unsigned)d);
      b_[v] = d >> 8;
      r_[v] = atomicAdd(&hist[b_[v]], 1);
    }
  }
  __syncthreads();
  for (int i = t; i < NBUCK; i += 256) {
    int h = hist[i];
    gbase[i] = h ? atomicAdd(&bcur[i], h) : 0;
  }
  __syncthreads();
  #pragma unroll
  for (int v = 0; v < 8; ++v)
    if (b_[v] >= 0)
      ebuf[(size_t)b_[v] * BCAP + gbase[b_[v]] + r_[v]] = p_[v];
}

// One WG per bucket; computes its own base via local prefix over bcur,
// builds off[] via LDS histogram+scan, then L2-local scatter into adj.
__global__ __launch_bounds__(256) void fill_local_kernel(
    const uint2* __restrict__ ebuf, const int* __restrict__ bcur,
    int* __restrict__ off, int* __restrict__ adj, int N)
{
  __shared__ int lhist[256], loff[256], lcur[256];
  __shared__ int wsum[4];
  __shared__ int sbase;
  const int b = blockIdx.x;
  const int t = threadIdx.x;
  const int wv = t >> 6, l = t & 63;
  const int cnt = bcur[b];
  const uint2* seg = ebuf + (size_t)b * BCAP;

  {
    int v = (t < NBUCK) ? bcur[t] : 0;
    int x = v;
    #pragma unroll
    for (int s = 1; s < 64; s <<= 1) {
      int y = __shfl_up(x, s, 64);
      if (l >= s) x += y;
    }
    if (l == 63) wsum[wv] = x;
    lhist[t] = 0; lcur[t] = 0;
    __syncthreads();
    int woff = 0;
    #pragma unroll
    for (int k = 0; k < 4; ++k) woff += (k < wv) ? wsum[k] : 0;
    if (t == b) sbase = woff + x - v;
  }
  __syncthreads();

  for (int i = t; i < cnt; i += 256)
    atomicAdd(&lhist[seg[i].y & 255], 1);
  __syncthreads();

  int v = lhist[t];
  int x = v;
  #pragma unroll
  for (int s = 1; s < 64; s <<= 1) {
    int y = __shfl_up(x, s, 64);
    if (l >= s) x += y;
  }
  if (l == 63) wsum[wv] = x;
  __syncthreads();
  int woff = 0;
  #pragma unroll
  for (int k = 0; k < 4; ++k) woff += (k < wv) ? wsum[k] : 0;
  loff[t] = woff + x - v;
  int gd = (b << 8) + t;
  if (gd <= N) off[gd] = sbase + loff[t];
  __syncthreads();
  const int base = sbase;
  for (int i = t; i < cnt; i += 256) {
    uint2 p = seg[i];
    int d = p.y & 255;
    int r = atomicAdd(&lcur[d], 1);
    adj[base + loff[d] + r] = (int)p.x;
  }
}

// ---------------- aggregation: one wave per dst node (fabric-floor-bound) --
__global__ __launch_bounds__(256) void aggregate_kernel(
    const unsigned short* __restrict__ featb, const int* __restrict__ adj,
    const int* __restrict__ off, const float* __restrict__ elp,
    const float* __restrict__ erp, void* __restrict__ outp,
    int N, int F, int mode)
{
  __shared__ float4 pl[4][64];
  int wv = threadIdx.x >> 6, l = threadIdx.x & 63;
  int n  = blockIdx.x * 4 + wv;
  if (n >= N) return;
  const int NC = HEADS * F;
  const unsigned rowbytes = NC * 2;
  int o0 = off[n], d = off[n + 1] - o0;
  float er0 = erp[n * 4 + 0], er1 = erp[n * 4 + 1], er2 = erp[n * 4 + 2];
  const float4* elv = (const float4*)elp;
  const char* fbase = (const char*)featb;
  const int gl = (F == 64) ? 48 : 30;
  const int h  = (F == 64) ? (l >> 4) : (l / 10);
  const unsigned loff2 = (unsigned)l * 8u;
  const float4* plw = pl[wv];

  float s0 = 0.f, s1 = 0.f, s2 = 0.f;
  float4 acc = {0.f, 0.f, 0.f, 0.f};

#define LDU(AA) (*(const uint2*)(fbase + (__float_as_uint((AA).x) + loff2)))
#define FMA4(AA, UU) { \
    float ww = (h == 0) ? (AA).y : (h == 1) ? (AA).z : (AA).w; \
    acc.x += ww * __uint_as_float((UU).x << 16); \
    acc.y += ww * __uint_as_float((UU).x & 0xffff0000u); \
    acc.z += ww * __uint_as_float((UU).y << 16); \
    acc.w += ww * __uint_as_float((UU).y & 0xffff0000u); }

  for (int base = 0; base < d; base += 64) {
    int i = base + l;
    float p0 = 0.f, p1 = 0.f, p2 = 0.f;
    unsigned boff = 0;
    if (i < d) {
      int ssrc = adj[o0 + i];
      boff = (unsigned)ssrc * rowbytes;
      float4 ev = elv[ssrc];
      float x0 = ev.x + er0; x0 = fmaxf(x0, 0.2f * x0);
      float x1 = ev.y + er1; x1 = fmaxf(x1, 0.2f * x1);
      float x2 = ev.z + er2; x2 = fmaxf(x2, 0.2f * x2);
      p0 = __expf(x0); p1 = __expf(x1); p2 = __expf(x2);
    }
    s0 += p0; s1 += p1; s2 += p2;
    pl[wv][l] = make_float4(__uint_as_float(boff), p0, p1, p2);

    int cnt = min(64, d - base);
    if (l < gl) {
      int e = 0;
      if (cnt >= 8) {
        float4 a0 = plw[0], a1 = plw[1], a2 = plw[2], a3 = plw[3];
        uint2 u0 = LDU(a0), u1 = LDU(a1), u2 = LDU(a2), u3 = LDU(a3);
        for (e = 4; e + 4 <= cnt; e += 4) {
          float4 b0 = plw[e], b1 = plw[e + 1], b2 = plw[e + 2], b3 = plw[e + 3];
          uint2 n0 = LDU(b0), n1 = LDU(b1), n2 = LDU(b2), n3 = LDU(b3);
          FMA4(a0, u0) FMA4(a1, u1) FMA4(a2, u2) FMA4(a3, u3)
          a0 = b0; a1 = b1; a2 = b2; a3 = b3;
          u0 = n0; u1 = n1; u2 = n2; u3 = n3;
        }
        FMA4(a0, u0) FMA4(a1, u1) FMA4(a2, u2) FMA4(a3, u3)
      }
      for (; e < cnt; ++e) {
        float4 a0 = plw[e];
        uint2 u0 = LDU(a0);
        FMA4(a0, u0)
      }
    }
  }
#undef LDU
#undef FMA4

  s0 = wred_sum(s0); s1 = wred_sum(s1); s2 = wred_sum(s2);
  float i0 = s0 > 0.f ? 1.f / s0 : 0.f;
  float i1 = s1 > 0.f ? 1.f / s1 : 0.f;
  float i2 = s2 > 0.f ? 1.f / s2 : 0.f;
  float ih = (h == 0) ? i0 : (h == 1) ? i1 : i2;
  acc.x *= ih; acc.y *= ih; acc.z *= ih; acc.w *= ih;

  if (mode == 0) {
    if (l < 48) {
      ushort4 o;
      o.x = f2bf(fmaxf(acc.x, 0.f)); o.y = f2bf(fmaxf(acc.y, 0.f));
      o.z = f2bf(fmaxf(acc.z, 0.f)); o.w = f2bf(fmaxf(acc.w, 0.f));
      *(ushort4*)((unsigned short*)outp + (size_t)n * 192 + l * 4) = o;
    }
  } else {
    float bx = __shfl(acc.x, l + 10, 64), cx = __shfl(acc.x, l + 20, 64);
    float by = __shfl(acc.y, l + 10, 64), cy = __shfl(acc.y, l + 20, 64);
    float bz = __shfl(acc.z, l + 10, 64), cz = __shfl(acc.z, l + 20, 64);
    float bw = __shfl(acc.w, l + 10, 64), cw = __shfl(acc.w, l + 20, 64);
    if (l < 10) {
      float4 o;
      o.x = (acc.x + bx + cx) * (1.f / 3.f);
      o.y = (acc.y + by + cy) * (1.f / 3.f);
      o.z = (acc.z + bz + cz) * (1.f / 3.f);
      o.w = (acc.w + bw + cw) * (1.f / 3.f);
      *(float4*)((float*)outp + (size_t)n * 40 + l * 4) = o;
    }
  }
}

extern "C" void kernel_launch(void* const* d_in, const int* in_sizes, int n_in,
                              void* d_out, int out_size, void* d_ws, size_t ws_size,
                              hipStream_t stream) {
  const float* x   = (const float*)d_in[0];
  const int*   src = (const int*)d_in[1];
  const int*   dst = (const int*)d_in[2];
  const float* W0  = (const float*)d_in[3];
  const float* al0 = (const float*)d_in[4];
  const float* ar0 = (const float*)d_in[5];
  const float* W1  = (const float*)d_in[6];
  const float* al1 = (const float*)d_in[7];
  const float* ar1 = (const float*)d_in[8];
  const float* W2  = (const float*)d_in[9];
  const float* al2 = (const float*)d_in[10];
  const float* ar2 = (const float*)d_in[11];
  const int N = NNODES;
  const int E = in_sizes[1];
  float* out = (float*)d_out;

  char* w = (char*)d_ws;
  uint2*          ebuf  = (uint2*)w;          w += (size_t)NBUCK * BCAP * 8;    // 25.6MB
  unsigned short* featb = (unsigned short*)w; w += (size_t)N * 192 * 2;         // 19.2MB
  unsigned short* aggb  = (unsigned short*)w; w += (size_t)N * 192 * 2 + 65536; // 19.2MB+pad (OOB stage reads)
  unsigned short* Bf    = (unsigned short*)w; w += (size_t)256 * 1024;          // 256KB
  float* elp = (float*)w; w += (size_t)N * 4 * 4;
  float* erp = (float*)w; w += (size_t)N * 4 * 4;
  int* off   = (int*)w;  w += (size_t)(N + 1) * 4;
  int* adj   = (int*)w;  w += (size_t)E * 4;
  int* bcur  = (int*)w;  w += (size_t)NBUCK * 4;

  // weight prep (layers 0-2) + bcur zeroing (layer 3) in one launch
  prep_b_all_kernel<<<dim3(26, 4), 256, 0, stream>>>(W0, al0, ar0, W1, al1, ar1,
                                                     W2, al2, ar2, Bf, bcur);

  // CSR build via bucket partition (all scatters L2-local)
  partition_kernel<<<(E + 2047) / 2048, 256, 0, stream>>>(src, dst, bcur, ebuf, E);
  fill_local_kernel<<<NBUCK, 256, 0, stream>>>(ebuf, bcur, off, adj, N);

  int gblk = (N + 31) / 32;
  int ablk = (N + 3) / 4;

  // layer 0: fp32 A, cvt fused into LDS stage; K=256, NT=13 (192 feat + el/er)
  gemm_mfma_kernel<256, 1><<<gblk, 256, 0, stream>>>(x, Bf, featb, elp, erp, N, 13, 192);
  aggregate_kernel<<<ablk, 256, 0, stream>>>(featb, adj, off, elp, erp, aggb, N, 64, 0);
  // layer 1: K=192, NT=13
  gemm_mfma_kernel<192, 0><<<gblk, 256, 0, stream>>>(aggb, Bf + 53248, featb, elp, erp, N, 13, 192);
  aggregate_kernel<<<ablk, 256, 0, stream>>>(featb, adj, off, elp, erp, aggb, N, 64, 0);
  // layer 2: K=192, NT=8 (120 feat cols + el/er in tile 7)
  gemm_mfma_kernel<192, 0><<<gblk, 256, 0, stream>>>(aggb, Bf + 93184, featb, elp, erp, N, 8, 120);
  aggregate_kernel<<<ablk, 256, 0, stream>>>(featb, adj, off, elp, erp, out, N, 40, 1);
}